// Round 6
// baseline (112.865 us; speedup 1.0000x reference)
//
#include <hip/hip_runtime.h>
#include <hip/hip_bf16.h>

// UncompressTransformLayer: scatter compressed strict-upper-triangular vector
// (row-major triu order, k=1) into a dense [n,n] fp32 matrix, zeros elsewhere.
// n = 8192, m = n*(n-1)/2 = 33,550,336.
//
// Memory-bound: 256 MiB write (all of out, every call) + 128 MiB read.
// Floor ~ 402 MB / 6.3 TB/s ~ 64 us; phase-split floor ~62 us.
// R1: scalar reads, plain stores            -> 100 us (4.0 TB/s)
// R2: nt stores + 8-wide units              -> 116 us (regressed; reverted)
// R3: aligned f32x4-pair + funnel select    ->  93 us (4.3 TB/s)
// R4: 64B/thread chunks + unaligned reads   -> 131 us (lane stride must be 16B!)
// R5: one unaligned dwordx4 per quad        -> 100 us (misaligned 16B splits)
// R6: R3 split into TWO pure-stream kernels: Z (write-only triangular fill)
//     then C (1:1 read:write copy) -- removes read/write stream mixing.

#define N_DIM 8192
#define M_TOTAL 33550336u
#define QUADS_PER_ROW (N_DIM / 4)            // 2048
#define TOTAL_QUADS (N_DIM * QUADS_PER_ROW)  // 16,777,216 (fits u32)

typedef float f32x4 __attribute__((ext_vector_type(4)));

// ---- Kernel Z: zero-fill all quads strictly below the diagonal ----
__global__ void __launch_bounds__(256)
zero_kernel(float* __restrict__ out) {
    const unsigned stride = gridDim.x * blockDim.x;
    for (unsigned q = blockIdx.x * blockDim.x + threadIdx.x;
         q < (unsigned)TOTAL_QUADS; q += stride) {
        const unsigned i  = q >> 11;
        const unsigned j0 = (q & 2047u) << 2;
        if (j0 + 3u <= i) {
            *reinterpret_cast<f32x4*>(out + ((size_t)i << 13) + j0) = (f32x4)0.f;
        }
    }
}

// ---- Kernel C: copy compressed data into quads touching the upper triangle ----
__global__ void __launch_bounds__(256)
copy_kernel(const float* __restrict__ comp, float* __restrict__ out) {
    const unsigned stride = gridDim.x * blockDim.x;
    for (unsigned q = blockIdx.x * blockDim.x + threadIdx.x;
         q < (unsigned)TOTAL_QUADS; q += stride) {
        const unsigned i  = q >> 11;
        const unsigned j0 = (q & 2047u) << 2;
        if (j0 + 3u > i) {                     // complement of zero_kernel
            // idx = Offset(i) + (j - i - 1), Offset(i) = i*(n-1) - i*(i-1)/2
            // base = Offset(i) - i - 1  (idx = base + j)
            const unsigned off  = i * (N_DIM - 1) - ((i * (i - 1u)) >> 1);
            const unsigned base = off - i - 1u;
            f32x4 v4;
            if (j0 > i) {
                // fully above diagonal: aligned 16B pair + row-uniform funnel
                // (each wave of 64 quads sits inside one row: 2048 quads/row)
                const unsigned c0 = base + j0;
                const unsigned al = c0 & ~3u;
                const unsigned r  = __builtin_amdgcn_readfirstlane(c0 & 3u);
                const f32x4 v = *reinterpret_cast<const f32x4*>(comp + al);
                const unsigned wi = (al + 4u <= M_TOTAL - 4u) ? (al + 4u)
                                                              : (M_TOTAL - 4u);
                const f32x4 w = *reinterpret_cast<const f32x4*>(comp + wi);
                switch (r) {
                    case 0: v4 = v; break;
                    case 1: v4 = (f32x4){v.y, v.z, v.w, w.x}; break;
                    case 2: v4 = (f32x4){v.z, v.w, w.x, w.y}; break;
                    default: v4 = (f32x4){v.w, w.x, w.y, w.z}; break;
                }
            } else {
                // straddles the diagonal (1 quad per row): predicated mix
                v4.x = (j0 + 0u > i) ? comp[base + j0 + 0u] : 0.f;
                v4.y = (j0 + 1u > i) ? comp[base + j0 + 1u] : 0.f;
                v4.z = (j0 + 2u > i) ? comp[base + j0 + 2u] : 0.f;
                v4.w = (j0 + 3u > i) ? comp[base + j0 + 3u] : 0.f;
            }
            *reinterpret_cast<f32x4*>(out + ((size_t)i << 13) + j0) = v4;
        }
    }
}

extern "C" void kernel_launch(void* const* d_in, const int* in_sizes, int n_in,
                              void* d_out, int out_size, void* d_ws, size_t ws_size,
                              hipStream_t stream) {
    const float* comp = (const float*)d_in[0];
    float* out = (float*)d_out;

    // 2048 blocks x 256 threads = 32 waves/CU; sequential on stream so the
    // HBM sees one pure write stream, then one pure 1:1 copy stream.
    const int block = 256;
    const int grid  = 2048;
    zero_kernel<<<grid, block, 0, stream>>>(out);
    copy_kernel<<<grid, block, 0, stream>>>(comp, out);
}